// Round 1
// baseline (339.231 us; speedup 1.0000x reference)
//
#include <hip/hip_runtime.h>
#include <math.h>

#define TOK   16384   // Bf * hw
#define HW    4096
#define C     128
#define D     64
#define HID   256
#define NB    4

constexpr float LN_EPS = 1e-5f;
constexpr float EPS_R  = 1e-10f;
constexpr float QSCALE = 0.08838834764831845f; // 128^-0.5

// ---------------- K1: transpose (NCHW -> token-major) + LayerNorm1 ----------------
__global__ __launch_bounds__(256) void k_ln1(const float* __restrict__ feat,
    const float* __restrict__ g, const float* __restrict__ b,
    float* __restrict__ xn, float* __restrict__ xtm) {
  __shared__ float tile[64][C + 1];
  int t0 = blockIdx.x * 64;
  int n = t0 / HW, i0 = t0 % HW;
  int tid = threadIdx.x;
  const float* fb = feat + (size_t)n * C * HW;
  for (int e = tid; e < 64 * C; e += 256) {
    int ch = e >> 6, ii = e & 63;
    tile[ii][ch] = fb[(size_t)ch * HW + i0 + ii];
  }
  __syncthreads();
  int wave = tid >> 6, lane = tid & 63;
  for (int tkn = wave; tkn < 64; tkn += 4) {
    float a0 = tile[tkn][lane];
    float a1 = tile[tkn][lane + 64];
    float s = a0 + a1;
    for (int off = 32; off; off >>= 1) s += __shfl_xor(s, off, 64);
    float mean = s * (1.0f / 128.0f);
    float d0 = a0 - mean, d1 = a1 - mean;
    float v = d0 * d0 + d1 * d1;
    for (int off = 32; off; off >>= 1) v += __shfl_xor(v, off, 64);
    float rstd = rsqrtf(v * (1.0f / 128.0f) + LN_EPS);
    size_t ro = (size_t)(t0 + tkn) * C;
    xn[ro + lane]       = d0 * rstd * g[lane] + b[lane];
    xn[ro + lane + 64]  = d1 * rstd * g[lane + 64] + b[lane + 64];
    xtm[ro + lane]      = a0;
    xtm[ro + lane + 64] = a1;
  }
}

// ---------------- K2: fused QKV GEMM (reuse A tile; K/V view-swapped; Q scaled) ----
__global__ __launch_bounds__(256) void k_qkv(const float* __restrict__ xn,
    const float* __restrict__ wq, const float* __restrict__ bq,
    const float* __restrict__ wk, const float* __restrict__ bk,
    const float* __restrict__ wv, const float* __restrict__ bv,
    float* __restrict__ q, float* __restrict__ ksw, float* __restrict__ vsw) {
  __shared__ float As[64][C];
  int t0 = blockIdx.x * 64;
  int tid = threadIdx.x;
  const float* src = xn + (size_t)t0 * C;
  for (int e = tid; e < 64 * C; e += 256) As[e >> 7][e & 127] = src[e];
  __syncthreads();
  int tc = tid & 31, tr = tid >> 5;
  int n = t0 / HW, i0 = t0 % HW;
  int tswap = (n ^ 1) * HW + i0;
  const float* Ws[3] = {wq, wk, wv};
  const float* Bs[3] = {bq, bk, bv};
  float* Os[3] = {q, ksw, vsw};
  #pragma unroll
  for (int m = 0; m < 3; ++m) {
    const float* W = Ws[m];
    float acc[8][4];
    #pragma unroll
    for (int i = 0; i < 8; i++)
      #pragma unroll
      for (int j = 0; j < 4; j++) acc[i][j] = 0.f;
    for (int kk = 0; kk < C; ++kk) {
      float4 w4 = *(const float4*)(W + (size_t)kk * C + tc * 4);
      #pragma unroll
      for (int i = 0; i < 8; i++) {
        float a = As[tr * 8 + i][kk];
        acc[i][0] += a * w4.x; acc[i][1] += a * w4.y;
        acc[i][2] += a * w4.z; acc[i][3] += a * w4.w;
      }
    }
    float4 b4 = *(const float4*)(Bs[m] + tc * 4);
    float sc = (m == 0) ? QSCALE : 1.f;
    int base = (m == 0) ? t0 : tswap;
    float* O = Os[m];
    #pragma unroll
    for (int i = 0; i < 8; i++) {
      float4 o;
      o.x = (acc[i][0] + b4.x) * sc;
      o.y = (acc[i][1] + b4.y) * sc;
      o.z = (acc[i][2] + b4.z) * sc;
      o.w = (acc[i][3] + b4.w) * sc;
      *(float4*)(O + (size_t)(base + tr * 8 + i) * C + tc * 4) = o;
    }
  }
}

// ---------------- K3: gather attention (one wave per token) -----------------------
__global__ __launch_bounds__(256) void k_attn(const float* __restrict__ q,
    const float* __restrict__ ksw, const float* __restrict__ vsw,
    const int* __restrict__ widx, const float* __restrict__ dprob,
    const float* __restrict__ kpe, const float* __restrict__ vpe,
    const float* __restrict__ rpe, float* __restrict__ out) {
  __shared__ float Qs[4][C];
  __shared__ float attn_s[4][D];
  __shared__ int   idx_s[4][D];
  int wave = threadIdx.x >> 6, lane = threadIdx.x & 63;
  int token = blockIdx.x * 4 + wave;
  int n = token >> 12;            // token / HW
  const float* Kb = ksw + (size_t)n * HW * C;
  const float* Vb = vsw + (size_t)n * HW * C;
  float q0 = q[(size_t)token * C + lane];
  float q1 = q[(size_t)token * C + lane + 64];
  Qs[wave][lane] = q0;
  Qs[wave][lane + 64] = q1;
  float qpe = q0 + q1;
  for (int off = 32; off; off >>= 1) qpe += __shfl_xor(qpe, off, 64);
  size_t ib = (size_t)token * D + lane;
  int myidx = widx[ib];
  float mydp = dprob[ib];
  idx_s[wave][lane] = myidx;
  __syncthreads();
  // cost[lane] = dot(Q, K[idx[lane]]) + qpe*kpe[lane] + rpe[lane]
  const float* Krow = Kb + (size_t)myidx * C;
  float cost = 0.f;
  #pragma unroll 8
  for (int c4 = 0; c4 < 32; ++c4) {
    float4 kv = *(const float4*)(Krow + c4 * 4);
    cost += Qs[wave][c4 * 4 + 0] * kv.x + Qs[wave][c4 * 4 + 1] * kv.y
          + Qs[wave][c4 * 4 + 2] * kv.z + Qs[wave][c4 * 4 + 3] * kv.w;
  }
  cost += qpe * kpe[lane] + rpe[lane];
  // softmax over 64 lanes
  float mx = cost;
  for (int off = 32; off; off >>= 1) mx = fmaxf(mx, __shfl_xor(mx, off, 64));
  float e = __expf(cost - mx);
  float s = e;
  for (int off = 32; off; off >>= 1) s += __shfl_xor(s, off, 64);
  float attn = e / s;
  attn *= mydp;
  float s2 = attn;
  for (int off = 32; off; off >>= 1) s2 += __shfl_xor(s2, off, 64);
  attn = (attn + EPS_R) / (s2 + EPS_R);
  float vpt = attn * vpe[lane];
  for (int off = 32; off; off >>= 1) vpt += __shfl_xor(vpt, off, 64);
  attn_s[wave][lane] = attn;
  __syncthreads();
  // AmV: coalesced per-channel accumulation
  float o0 = vpt, o1 = vpt;
  #pragma unroll 4
  for (int kk = 0; kk < D; ++kk) {
    float a = attn_s[wave][kk];
    const float* Vrow = Vb + (size_t)idx_s[wave][kk] * C;
    o0 += a * Vrow[lane];
    o1 += a * Vrow[lane + 64];
  }
  out[(size_t)token * C + lane]      = o0;
  out[(size_t)token * C + lane + 64] = o1;
}

// ---------------- K4: proj GEMM + residual (in-place on shortcut buffer) ----------
__global__ __launch_bounds__(256) void k_proj(const float* __restrict__ ain,
    const float* __restrict__ W, const float* __restrict__ bias, float* xio) {
  __shared__ float As[64][C];
  int t0 = blockIdx.x * 64;
  int tid = threadIdx.x;
  const float* src = ain + (size_t)t0 * C;
  for (int e = tid; e < 64 * C; e += 256) As[e >> 7][e & 127] = src[e];
  __syncthreads();
  int tc = tid & 31, tr = tid >> 5;
  float acc[8][4];
  #pragma unroll
  for (int i = 0; i < 8; i++)
    #pragma unroll
    for (int j = 0; j < 4; j++) acc[i][j] = 0.f;
  for (int kk = 0; kk < C; ++kk) {
    float4 w4 = *(const float4*)(W + (size_t)kk * C + tc * 4);
    #pragma unroll
    for (int i = 0; i < 8; i++) {
      float a = As[tr * 8 + i][kk];
      acc[i][0] += a * w4.x; acc[i][1] += a * w4.y;
      acc[i][2] += a * w4.z; acc[i][3] += a * w4.w;
    }
  }
  float4 b4 = *(const float4*)(bias + tc * 4);
  #pragma unroll
  for (int i = 0; i < 8; i++) {
    size_t ro = (size_t)(t0 + tr * 8 + i) * C + tc * 4;
    float4 sc4 = *(const float4*)(xio + ro);
    float4 o;
    o.x = acc[i][0] + b4.x + sc4.x;
    o.y = acc[i][1] + b4.y + sc4.y;
    o.z = acc[i][2] + b4.z + sc4.z;
    o.w = acc[i][3] + b4.w + sc4.w;
    *(float4*)(xio + ro) = o;
  }
}

// ---------------- K5: LayerNorm2 --------------------------------------------------
__global__ __launch_bounds__(256) void k_ln2(const float* __restrict__ x,
    const float* __restrict__ g, const float* __restrict__ b, float* __restrict__ xn2) {
  int wave = threadIdx.x >> 6, lane = threadIdx.x & 63;
  int tbase = blockIdx.x * 16 + wave * 4;
  for (int j = 0; j < 4; ++j) {
    size_t ro = (size_t)(tbase + j) * C;
    float a0 = x[ro + lane], a1 = x[ro + lane + 64];
    float s = a0 + a1;
    for (int off = 32; off; off >>= 1) s += __shfl_xor(s, off, 64);
    float mean = s * (1.0f / 128.0f);
    float d0 = a0 - mean, d1 = a1 - mean;
    float v = d0 * d0 + d1 * d1;
    for (int off = 32; off; off >>= 1) v += __shfl_xor(v, off, 64);
    float rstd = rsqrtf(v * (1.0f / 128.0f) + LN_EPS);
    xn2[ro + lane]      = d0 * rstd * g[lane] + b[lane];
    xn2[ro + lane + 64] = d1 * rstd * g[lane + 64] + b[lane + 64];
  }
}

__device__ __forceinline__ float gelu_exact(float x) {
  return 0.5f * x * (1.0f + erff(x * 0.7071067811865476f));
}

// ---------------- K6: fc1 GEMM + GELU ---------------------------------------------
__global__ __launch_bounds__(256) void k_fc1(const float* __restrict__ xn2,
    const float* __restrict__ W, const float* __restrict__ bias, float* __restrict__ y) {
  __shared__ float As[64][C];
  int t0 = blockIdx.x * 64;
  int c0 = blockIdx.y * 128;
  int tid = threadIdx.x;
  const float* src = xn2 + (size_t)t0 * C;
  for (int e = tid; e < 64 * C; e += 256) As[e >> 7][e & 127] = src[e];
  __syncthreads();
  int tc = tid & 31, tr = tid >> 5;
  float acc[8][4];
  #pragma unroll
  for (int i = 0; i < 8; i++)
    #pragma unroll
    for (int j = 0; j < 4; j++) acc[i][j] = 0.f;
  for (int kk = 0; kk < C; ++kk) {
    float4 w4 = *(const float4*)(W + (size_t)kk * HID + c0 + tc * 4);
    #pragma unroll
    for (int i = 0; i < 8; i++) {
      float a = As[tr * 8 + i][kk];
      acc[i][0] += a * w4.x; acc[i][1] += a * w4.y;
      acc[i][2] += a * w4.z; acc[i][3] += a * w4.w;
    }
  }
  float4 b4 = *(const float4*)(bias + c0 + tc * 4);
  #pragma unroll
  for (int i = 0; i < 8; i++) {
    float4 o;
    o.x = gelu_exact(acc[i][0] + b4.x);
    o.y = gelu_exact(acc[i][1] + b4.y);
    o.z = gelu_exact(acc[i][2] + b4.z);
    o.w = gelu_exact(acc[i][3] + b4.w);
    *(float4*)(y + (size_t)(t0 + tr * 8 + i) * HID + c0 + tc * 4) = o;
  }
}

// ---------------- K7: depthwise 5x5 conv + GELU (token-major in/out) --------------
__global__ __launch_bounds__(256) void k_dwconv(const float* __restrict__ y,
    const float* __restrict__ w, const float* __restrict__ bias, float* __restrict__ yc) {
  __shared__ float tile[20 * 20][8];
  __shared__ float wl[8][25];
  __shared__ float bl[8];
  int bid = blockIdx.x;
  int tile_id = bid & 15;
  int cb = (bid >> 4) & 31;
  int n = bid >> 9;
  int ty = (tile_id >> 2) * 16, tx = (tile_id & 3) * 16;
  int ch0 = cb * 8;
  int tid = threadIdx.x;
  if (tid < 200) wl[tid / 25][tid % 25] = w[(size_t)(ch0 + tid / 25) * 25 + tid % 25];
  if (tid < 8) bl[tid] = bias[ch0 + tid];
  const float* yb = y + (size_t)n * HW * HID;
  for (int e = tid; e < 400 * 8; e += 256) {
    int cc = e & 7;
    int p = e >> 3;
    int py = p / 20, px = p % 20;
    int gy = ty + py - 2, gx = tx + px - 2;
    float v = 0.f;
    if (gy >= 0 && gy < 64 && gx >= 0 && gx < 64)
      v = yb[(size_t)(gy * 64 + gx) * HID + ch0 + cc];
    tile[p][cc] = v;
  }
  __syncthreads();
  int cc = tid & 7;
  int xx = (tid >> 3) & 15;
  int yg = tid >> 7;
  float wreg[25];
  #pragma unroll
  for (int k = 0; k < 25; k++) wreg[k] = wl[cc][k];
  float bb = bl[cc];
  for (int j = 0; j < 8; ++j) {
    int yy = yg * 8 + j;
    float acc = 0.f;
    #pragma unroll
    for (int dy = 0; dy < 5; ++dy)
      #pragma unroll
      for (int dx = 0; dx < 5; ++dx)
        acc += wreg[dy * 5 + dx] * tile[(yy + dy) * 20 + (xx + dx)][cc];
    acc = gelu_exact(acc + bb);
    yc[(size_t)(n * HW + (ty + yy) * 64 + tx + xx) * HID + ch0 + cc] = acc;
  }
}

// ---------------- K8: fc2 GEMM on (y + yc) + final residual -> out ----------------
__global__ __launch_bounds__(256) void k_fc2(const float* __restrict__ ybuf,
    const float* __restrict__ yc, const float* __restrict__ W,
    const float* __restrict__ bias, const float* __restrict__ xbuf,
    float* __restrict__ outp) {
  __shared__ float As[64][HID];
  int t0 = blockIdx.x * 64;
  int tid = threadIdx.x;
  size_t base = (size_t)t0 * HID;
  for (int e = tid; e < 64 * HID; e += 256) As[e >> 8][e & 255] = ybuf[base + e] + yc[base + e];
  __syncthreads();
  int tc = tid & 31, tr = tid >> 5;
  float acc[8][4];
  #pragma unroll
  for (int i = 0; i < 8; i++)
    #pragma unroll
    for (int j = 0; j < 4; j++) acc[i][j] = 0.f;
  for (int kk = 0; kk < HID; ++kk) {
    float4 w4 = *(const float4*)(W + (size_t)kk * C + tc * 4);
    #pragma unroll
    for (int i = 0; i < 8; i++) {
      float a = As[tr * 8 + i][kk];
      acc[i][0] += a * w4.x; acc[i][1] += a * w4.y;
      acc[i][2] += a * w4.z; acc[i][3] += a * w4.w;
    }
  }
  float4 b4 = *(const float4*)(bias + tc * 4);
  #pragma unroll
  for (int i = 0; i < 8; i++) {
    size_t ro = (size_t)(t0 + tr * 8 + i) * C + tc * 4;
    float4 x4 = *(const float4*)(xbuf + ro);
    float4 o;
    o.x = acc[i][0] + b4.x + x4.x;
    o.y = acc[i][1] + b4.y + x4.y;
    o.z = acc[i][2] + b4.z + x4.z;
    o.w = acc[i][3] + b4.w + x4.w;
    *(float4*)(outp + ro) = o;
  }
}

extern "C" void kernel_launch(void* const* d_in, const int* in_sizes, int n_in,
                              void* d_out, int out_size, void* d_ws, size_t ws_size,
                              hipStream_t stream) {
  (void)in_sizes; (void)n_in; (void)out_size; (void)ws_size;
  const float* feat  = (const float*)d_in[0];
  const int*   widx  = (const int*)d_in[1];
  const float* dprob = (const float*)d_in[2];
  const float* ln1g  = (const float*)d_in[3];
  const float* ln1b  = (const float*)d_in[4];
  const float* wq    = (const float*)d_in[5];
  const float* bq    = (const float*)d_in[6];
  const float* wk    = (const float*)d_in[7];
  const float* bk    = (const float*)d_in[8];
  const float* wv    = (const float*)d_in[9];
  const float* bv    = (const float*)d_in[10];
  const float* kpe   = (const float*)d_in[11];
  const float* vpe   = (const float*)d_in[12];
  const float* rpe   = (const float*)d_in[13];
  const float* pw    = (const float*)d_in[14];
  const float* pb    = (const float*)d_in[15];
  const float* ln2g  = (const float*)d_in[16];
  const float* ln2b  = (const float*)d_in[17];
  const float* f1w   = (const float*)d_in[18];
  const float* f1b   = (const float*)d_in[19];
  const float* dww   = (const float*)d_in[20];
  const float* dwb   = (const float*)d_in[21];
  const float* f2w   = (const float*)d_in[22];
  const float* f2b   = (const float*)d_in[23];

  float* ws = (float*)d_ws;
  const size_t M2 = (size_t)TOK * C;       // 2,097,152 floats (8 MB)
  float* xn   = ws;                        // [0, M2)       K1w, K2r
  float* qb   = ws + M2;                   // [M2, 2M2)     K2w, K3r
  float* ksb  = ws + 2 * M2;               // [2M2, 3M2)    K2w, K3r
  float* vsb  = ws + 3 * M2;               // [3M2, 4M2)    K2w, K3r
  float* xio  = ws + 4 * M2;               // [4M2, 5M2)    shortcut (K1w,K4rw), x_buf (K5r,K8r)
  float* aout = ws;                        // alias xn      K3w, K4r
  float* xn2  = ws + M2;                   // alias qb      K5w, K6r
  float* ybuf = ws + 2 * M2;               // alias ks+vs (4M floats) K6w, K7r, K8r
  float* ycb  = ws + 5 * M2;               // [5M2, 7M2)    K7w, K8r
  // total workspace use: 7 * M2 * 4 B = 56 MB

  k_ln1  <<<TOK / 64, 256, 0, stream>>>(feat, ln1g, ln1b, xn, xio);
  k_qkv  <<<TOK / 64, 256, 0, stream>>>(xn, wq, bq, wk, bk, wv, bv, qb, ksb, vsb);
  k_attn <<<TOK / 4, 256, 0, stream>>>(qb, ksb, vsb, widx, dprob, kpe, vpe, rpe, aout);
  k_proj <<<TOK / 64, 256, 0, stream>>>(aout, pw, pb, xio);
  k_ln2  <<<TOK / 16, 256, 0, stream>>>(xio, ln2g, ln2b, xn2);
  k_fc1  <<<dim3(TOK / 64, 2), 256, 0, stream>>>(xn2, f1w, f1b, ybuf);
  k_dwconv<<<2048, 256, 0, stream>>>(ybuf, dww, dwb, ycb);
  k_fc2  <<<TOK / 64, 256, 0, stream>>>(ybuf, ycb, f2w, f2b, xio, (float*)d_out);
}

// Round 2
// 288.654 us; speedup vs baseline: 1.1752x; 1.1752x over previous
//
#include <hip/hip_runtime.h>
#include <math.h>

#define TOK   16384   // Bf * hw
#define HW    4096
#define C     128
#define D     64
#define HID   256

constexpr float LN_EPS = 1e-5f;
constexpr float EPS_R  = 1e-10f;
constexpr float QSCALE = 0.08838834764831845f; // 128^-0.5

__device__ __forceinline__ float bflo(unsigned u) { return __uint_as_float(u << 16); }
__device__ __forceinline__ float bfhi(unsigned u) { return __uint_as_float(u & 0xffff0000u); }
__device__ __forceinline__ unsigned short f2bf(float f) {
  unsigned u = __float_as_uint(f);
  unsigned r = (u + 0x7fffu + ((u >> 16) & 1u)) >> 16;
  return (unsigned short)r;
}

// ---------------- K1: transpose (NCHW -> token-major) + LayerNorm1 ----------------
__global__ __launch_bounds__(256) void k_ln1(const float* __restrict__ feat,
    const float* __restrict__ g, const float* __restrict__ b,
    float* __restrict__ xn, float* __restrict__ xtm) {
  __shared__ float tile[64][C + 1];
  int t0 = blockIdx.x * 64;
  int n = t0 / HW, i0 = t0 % HW;
  int tid = threadIdx.x;
  const float* fb = feat + (size_t)n * C * HW;
  for (int e = tid; e < 64 * C; e += 256) {
    int ch = e >> 6, ii = e & 63;
    tile[ii][ch] = fb[(size_t)ch * HW + i0 + ii];
  }
  __syncthreads();
  int wave = tid >> 6, lane = tid & 63;
  for (int tkn = wave; tkn < 64; tkn += 4) {
    float a0 = tile[tkn][lane];
    float a1 = tile[tkn][lane + 64];
    float s = a0 + a1;
    for (int off = 32; off; off >>= 1) s += __shfl_xor(s, off, 64);
    float mean = s * (1.0f / 128.0f);
    float d0 = a0 - mean, d1 = a1 - mean;
    float v = d0 * d0 + d1 * d1;
    for (int off = 32; off; off >>= 1) v += __shfl_xor(v, off, 64);
    float rstd = rsqrtf(v * (1.0f / 128.0f) + LN_EPS);
    size_t ro = (size_t)(t0 + tkn) * C;
    xn[ro + lane]       = d0 * rstd * g[lane] + b[lane];
    xn[ro + lane + 64]  = d1 * rstd * g[lane + 64] + b[lane + 64];
    xtm[ro + lane]      = a0;
    xtm[ro + lane + 64] = a1;
  }
}

// ---------------- K2: fused QKV GEMM (A-tile reuse; K/V bf16 + view-swapped) ------
__global__ __launch_bounds__(256) void k_qkv(const float* __restrict__ xn,
    const float* __restrict__ wq, const float* __restrict__ bq,
    const float* __restrict__ wk, const float* __restrict__ bk,
    const float* __restrict__ wv, const float* __restrict__ bv,
    float* __restrict__ q, unsigned short* __restrict__ ksw,
    unsigned short* __restrict__ vsw) {
  __shared__ float As[64][C];
  int t0 = blockIdx.x * 64;
  int tid = threadIdx.x;
  const float* src = xn + (size_t)t0 * C;
  for (int e = tid; e < 64 * C; e += 256) As[e >> 7][e & 127] = src[e];
  __syncthreads();
  int tc = tid & 31, tr = tid >> 5;
  int n = t0 / HW, i0 = t0 % HW;
  int tswap = (n ^ 1) * HW + i0;
  const float* Ws[3] = {wq, wk, wv};
  const float* Bs[3] = {bq, bk, bv};
  #pragma unroll
  for (int m = 0; m < 3; ++m) {
    const float* W = Ws[m];
    float acc[8][4];
    #pragma unroll
    for (int i = 0; i < 8; i++)
      #pragma unroll
      for (int j = 0; j < 4; j++) acc[i][j] = 0.f;
    for (int kk = 0; kk < C; ++kk) {
      float4 w4 = *(const float4*)(W + (size_t)kk * C + tc * 4);
      #pragma unroll
      for (int i = 0; i < 8; i++) {
        float a = As[tr * 8 + i][kk];
        acc[i][0] += a * w4.x; acc[i][1] += a * w4.y;
        acc[i][2] += a * w4.z; acc[i][3] += a * w4.w;
      }
    }
    float4 b4 = *(const float4*)(Bs[m] + tc * 4);
    if (m == 0) {
      #pragma unroll
      for (int i = 0; i < 8; i++) {
        float4 o;
        o.x = (acc[i][0] + b4.x) * QSCALE;
        o.y = (acc[i][1] + b4.y) * QSCALE;
        o.z = (acc[i][2] + b4.z) * QSCALE;
        o.w = (acc[i][3] + b4.w) * QSCALE;
        *(float4*)(q + (size_t)(t0 + tr * 8 + i) * C + tc * 4) = o;
      }
    } else {
      unsigned short* O = (m == 1) ? ksw : vsw;
      #pragma unroll
      for (int i = 0; i < 8; i++) {
        ushort4 o;
        o.x = f2bf(acc[i][0] + b4.x);
        o.y = f2bf(acc[i][1] + b4.y);
        o.z = f2bf(acc[i][2] + b4.z);
        o.w = f2bf(acc[i][3] + b4.w);
        *(ushort4*)(O + (size_t)(tswap + tr * 8 + i) * C + tc * 4) = o;
      }
    }
  }
}

// ---------------- K3: gather attention, bf16 K/V, coalesced, no LDS ---------------
// One wave per token. QmK: 8 passes, each pass 8 rows read cooperatively
// (8 lanes x 16 channels per row), 3-step group shuffle reduce.
__global__ __launch_bounds__(256) void k_attn(const float* __restrict__ q,
    const unsigned short* __restrict__ ksw, const unsigned short* __restrict__ vsw,
    const int* __restrict__ widx, const float* __restrict__ dprob,
    const float* __restrict__ kpe, const float* __restrict__ vpe,
    const float* __restrict__ rpe, float* __restrict__ out) {
  int lane = threadIdx.x & 63;
  int wave = threadIdx.x >> 6;
  int token = blockIdx.x * 4 + wave;
  int n = token >> 12;                   // token / HW
  const unsigned short* Kb = ksw + (size_t)n * HW * C;
  const unsigned short* Vb = vsw + (size_t)n * HW * C;
  int g = lane >> 3, s = lane & 7;
  // Q segment for this lane: channels [s*16, s*16+16)  (pre-scaled)
  float qreg[16];
  const float* qp = q + (size_t)token * C + s * 16;
  #pragma unroll
  for (int i = 0; i < 4; i++) {
    float4 t = *(const float4*)(qp + i * 4);
    qreg[i * 4 + 0] = t.x; qreg[i * 4 + 1] = t.y;
    qreg[i * 4 + 2] = t.z; qreg[i * 4 + 3] = t.w;
  }
  float qpe = 0.f;
  #pragma unroll
  for (int i = 0; i < 16; i++) qpe += qreg[i];
  qpe += __shfl_xor(qpe, 1, 64);
  qpe += __shfl_xor(qpe, 2, 64);
  qpe += __shfl_xor(qpe, 4, 64);        // full Q-sum (segments live in s=0..7)
  int myidx = widx[token * D + lane];
  float mydp = dprob[token * D + lane];
  float mycost = 0.f;
  #pragma unroll
  for (int pass = 0; pass < 8; ++pass) {
    int row = __shfl(myidx, pass * 8 + g, 64);
    const unsigned short* kr = Kb + (size_t)row * C + s * 16;
    uint4 ka = *(const uint4*)(kr);
    uint4 kb = *(const uint4*)(kr + 8);
    float p;
    p  = bflo(ka.x) * qreg[0]  + bfhi(ka.x) * qreg[1];
    p += bflo(ka.y) * qreg[2]  + bfhi(ka.y) * qreg[3];
    p += bflo(ka.z) * qreg[4]  + bfhi(ka.z) * qreg[5];
    p += bflo(ka.w) * qreg[6]  + bfhi(ka.w) * qreg[7];
    p += bflo(kb.x) * qreg[8]  + bfhi(kb.x) * qreg[9];
    p += bflo(kb.y) * qreg[10] + bfhi(kb.y) * qreg[11];
    p += bflo(kb.z) * qreg[12] + bfhi(kb.z) * qreg[13];
    p += bflo(kb.w) * qreg[14] + bfhi(kb.w) * qreg[15];
    p += __shfl_xor(p, 1, 64);
    p += __shfl_xor(p, 2, 64);
    p += __shfl_xor(p, 4, 64);          // all 8 lanes of group g now hold cost[pass*8+g]
    float t = __shfl(p, (lane & 7) << 3, 64);  // grab cost[pass*8 + (lane&7)]
    if (pass == g) mycost = t;          // lane kk ends with cost[kk]
  }
  mycost += qpe * kpe[lane] + rpe[lane];
  // softmax over 64 lanes
  float mx = mycost;
  for (int off = 32; off; off >>= 1) mx = fmaxf(mx, __shfl_xor(mx, off, 64));
  float e = __expf(mycost - mx);
  float ssum = e;
  for (int off = 32; off; off >>= 1) ssum += __shfl_xor(ssum, off, 64);
  float attn = (e / ssum) * mydp;
  float s2 = attn;
  for (int off = 32; off; off >>= 1) s2 += __shfl_xor(s2, off, 64);
  attn = (attn + EPS_R) / (s2 + EPS_R);
  float vpt = attn * vpe[lane];
  for (int off = 32; off; off >>= 1) vpt += __shfl_xor(vpt, off, 64);
  // AmV: coalesced bf16 row reads; attn/idx broadcast via shuffle
  float o0 = vpt, o1 = vpt;
  #pragma unroll 8
  for (int kk = 0; kk < D; ++kk) {
    int row = __shfl(myidx, kk, 64);
    float a = __shfl(attn, kk, 64);
    unsigned v = *(const unsigned*)(Vb + (size_t)row * C + lane * 2);
    o0 += a * bflo(v);
    o1 += a * bfhi(v);
  }
  float2 o2 = make_float2(o0, o1);
  *(float2*)(out + (size_t)token * C + lane * 2) = o2;
}

// ---------------- K4: proj GEMM + residual (in-place on shortcut buffer) ----------
__global__ __launch_bounds__(256) void k_proj(const float* __restrict__ ain,
    const float* __restrict__ W, const float* __restrict__ bias, float* xio) {
  __shared__ float As[64][C];
  int t0 = blockIdx.x * 64;
  int tid = threadIdx.x;
  const float* src = ain + (size_t)t0 * C;
  for (int e = tid; e < 64 * C; e += 256) As[e >> 7][e & 127] = src[e];
  __syncthreads();
  int tc = tid & 31, tr = tid >> 5;
  float acc[8][4];
  #pragma unroll
  for (int i = 0; i < 8; i++)
    #pragma unroll
    for (int j = 0; j < 4; j++) acc[i][j] = 0.f;
  for (int kk = 0; kk < C; ++kk) {
    float4 w4 = *(const float4*)(W + (size_t)kk * C + tc * 4);
    #pragma unroll
    for (int i = 0; i < 8; i++) {
      float a = As[tr * 8 + i][kk];
      acc[i][0] += a * w4.x; acc[i][1] += a * w4.y;
      acc[i][2] += a * w4.z; acc[i][3] += a * w4.w;
    }
  }
  float4 b4 = *(const float4*)(bias + tc * 4);
  #pragma unroll
  for (int i = 0; i < 8; i++) {
    size_t ro = (size_t)(t0 + tr * 8 + i) * C + tc * 4;
    float4 sc4 = *(const float4*)(xio + ro);
    float4 o;
    o.x = acc[i][0] + b4.x + sc4.x;
    o.y = acc[i][1] + b4.y + sc4.y;
    o.z = acc[i][2] + b4.z + sc4.z;
    o.w = acc[i][3] + b4.w + sc4.w;
    *(float4*)(xio + ro) = o;
  }
}

// ---------------- K5: LayerNorm2 --------------------------------------------------
__global__ __launch_bounds__(256) void k_ln2(const float* __restrict__ x,
    const float* __restrict__ g, const float* __restrict__ b, float* __restrict__ xn2) {
  int wave = threadIdx.x >> 6, lane = threadIdx.x & 63;
  int tbase = blockIdx.x * 16 + wave * 4;
  for (int j = 0; j < 4; ++j) {
    size_t ro = (size_t)(tbase + j) * C;
    float a0 = x[ro + lane], a1 = x[ro + lane + 64];
    float s = a0 + a1;
    for (int off = 32; off; off >>= 1) s += __shfl_xor(s, off, 64);
    float mean = s * (1.0f / 128.0f);
    float d0 = a0 - mean, d1 = a1 - mean;
    float v = d0 * d0 + d1 * d1;
    for (int off = 32; off; off >>= 1) v += __shfl_xor(v, off, 64);
    float rstd = rsqrtf(v * (1.0f / 128.0f) + LN_EPS);
    xn2[ro + lane]      = d0 * rstd * g[lane] + b[lane];
    xn2[ro + lane + 64] = d1 * rstd * g[lane + 64] + b[lane + 64];
  }
}

__device__ __forceinline__ float gelu_exact(float x) {
  return 0.5f * x * (1.0f + erff(x * 0.7071067811865476f));
}

// ---------------- K6: fc1 GEMM + GELU ---------------------------------------------
__global__ __launch_bounds__(256) void k_fc1(const float* __restrict__ xn2,
    const float* __restrict__ W, const float* __restrict__ bias, float* __restrict__ y) {
  __shared__ float As[64][C];
  int t0 = blockIdx.x * 64;
  int c0 = blockIdx.y * 128;
  int tid = threadIdx.x;
  const float* src = xn2 + (size_t)t0 * C;
  for (int e = tid; e < 64 * C; e += 256) As[e >> 7][e & 127] = src[e];
  __syncthreads();
  int tc = tid & 31, tr = tid >> 5;
  float acc[8][4];
  #pragma unroll
  for (int i = 0; i < 8; i++)
    #pragma unroll
    for (int j = 0; j < 4; j++) acc[i][j] = 0.f;
  for (int kk = 0; kk < C; ++kk) {
    float4 w4 = *(const float4*)(W + (size_t)kk * HID + c0 + tc * 4);
    #pragma unroll
    for (int i = 0; i < 8; i++) {
      float a = As[tr * 8 + i][kk];
      acc[i][0] += a * w4.x; acc[i][1] += a * w4.y;
      acc[i][2] += a * w4.z; acc[i][3] += a * w4.w;
    }
  }
  float4 b4 = *(const float4*)(bias + c0 + tc * 4);
  #pragma unroll
  for (int i = 0; i < 8; i++) {
    float4 o;
    o.x = gelu_exact(acc[i][0] + b4.x);
    o.y = gelu_exact(acc[i][1] + b4.y);
    o.z = gelu_exact(acc[i][2] + b4.z);
    o.w = gelu_exact(acc[i][3] + b4.w);
    *(float4*)(y + (size_t)(t0 + tr * 8 + i) * HID + c0 + tc * 4) = o;
  }
}

// ---------------- K7: depthwise 5x5 conv + GELU (token-major in/out) --------------
__global__ __launch_bounds__(256) void k_dwconv(const float* __restrict__ y,
    const float* __restrict__ w, const float* __restrict__ bias, float* __restrict__ yc) {
  __shared__ float tile[20 * 20][8];
  __shared__ float wl[8][25];
  __shared__ float bl[8];
  int bid = blockIdx.x;
  int tile_id = bid & 15;
  int cb = (bid >> 4) & 31;
  int n = bid >> 9;
  int ty = (tile_id >> 2) * 16, tx = (tile_id & 3) * 16;
  int ch0 = cb * 8;
  int tid = threadIdx.x;
  if (tid < 200) wl[tid / 25][tid % 25] = w[(size_t)(ch0 + tid / 25) * 25 + tid % 25];
  if (tid < 8) bl[tid] = bias[ch0 + tid];
  const float* yb = y + (size_t)n * HW * HID;
  for (int e = tid; e < 400 * 8; e += 256) {
    int cc = e & 7;
    int p = e >> 3;
    int py = p / 20, px = p % 20;
    int gy = ty + py - 2, gx = tx + px - 2;
    float v = 0.f;
    if (gy >= 0 && gy < 64 && gx >= 0 && gx < 64)
      v = yb[(size_t)(gy * 64 + gx) * HID + ch0 + cc];
    tile[p][cc] = v;
  }
  __syncthreads();
  int cc = tid & 7;
  int xx = (tid >> 3) & 15;
  int yg = tid >> 7;
  float wreg[25];
  #pragma unroll
  for (int k = 0; k < 25; k++) wreg[k] = wl[cc][k];
  float bb = bl[cc];
  for (int j = 0; j < 8; ++j) {
    int yy = yg * 8 + j;
    float acc = 0.f;
    #pragma unroll
    for (int dy = 0; dy < 5; ++dy)
      #pragma unroll
      for (int dx = 0; dx < 5; ++dx)
        acc += wreg[dy * 5 + dx] * tile[(yy + dy) * 20 + (xx + dx)][cc];
    acc = gelu_exact(acc + bb);
    yc[(size_t)(n * HW + (ty + yy) * 64 + tx + xx) * HID + ch0 + cc] = acc;
  }
}

// ---------------- K8: fc2 GEMM on (y + yc) + final residual -> out ----------------
__global__ __launch_bounds__(256) void k_fc2(const float* __restrict__ ybuf,
    const float* __restrict__ yc, const float* __restrict__ W,
    const float* __restrict__ bias, const float* __restrict__ xbuf,
    float* __restrict__ outp) {
  __shared__ float As[64][HID];
  int t0 = blockIdx.x * 64;
  int tid = threadIdx.x;
  size_t base = (size_t)t0 * HID;
  for (int e = tid; e < 64 * HID; e += 256) As[e >> 8][e & 255] = ybuf[base + e] + yc[base + e];
  __syncthreads();
  int tc = tid & 31, tr = tid >> 5;
  float acc[8][4];
  #pragma unroll
  for (int i = 0; i < 8; i++)
    #pragma unroll
    for (int j = 0; j < 4; j++) acc[i][j] = 0.f;
  for (int kk = 0; kk < HID; ++kk) {
    float4 w4 = *(const float4*)(W + (size_t)kk * C + tc * 4);
    #pragma unroll
    for (int i = 0; i < 8; i++) {
      float a = As[tr * 8 + i][kk];
      acc[i][0] += a * w4.x; acc[i][1] += a * w4.y;
      acc[i][2] += a * w4.z; acc[i][3] += a * w4.w;
    }
  }
  float4 b4 = *(const float4*)(bias + tc * 4);
  #pragma unroll
  for (int i = 0; i < 8; i++) {
    size_t ro = (size_t)(t0 + tr * 8 + i) * C + tc * 4;
    float4 x4 = *(const float4*)(xbuf + ro);
    float4 o;
    o.x = acc[i][0] + b4.x + x4.x;
    o.y = acc[i][1] + b4.y + x4.y;
    o.z = acc[i][2] + b4.z + x4.z;
    o.w = acc[i][3] + b4.w + x4.w;
    *(float4*)(outp + ro) = o;
  }
}

extern "C" void kernel_launch(void* const* d_in, const int* in_sizes, int n_in,
                              void* d_out, int out_size, void* d_ws, size_t ws_size,
                              hipStream_t stream) {
  (void)in_sizes; (void)n_in; (void)out_size; (void)ws_size;
  const float* feat  = (const float*)d_in[0];
  const int*   widx  = (const int*)d_in[1];
  const float* dprob = (const float*)d_in[2];
  const float* ln1g  = (const float*)d_in[3];
  const float* ln1b  = (const float*)d_in[4];
  const float* wq    = (const float*)d_in[5];
  const float* bq    = (const float*)d_in[6];
  const float* wk    = (const float*)d_in[7];
  const float* bk    = (const float*)d_in[8];
  const float* wv    = (const float*)d_in[9];
  const float* bv    = (const float*)d_in[10];
  const float* kpe   = (const float*)d_in[11];
  const float* vpe   = (const float*)d_in[12];
  const float* rpe   = (const float*)d_in[13];
  const float* pw    = (const float*)d_in[14];
  const float* pb    = (const float*)d_in[15];
  const float* ln2g  = (const float*)d_in[16];
  const float* ln2b  = (const float*)d_in[17];
  const float* f1w   = (const float*)d_in[18];
  const float* f1b   = (const float*)d_in[19];
  const float* dww   = (const float*)d_in[20];
  const float* dwb   = (const float*)d_in[21];
  const float* f2w   = (const float*)d_in[22];
  const float* f2b   = (const float*)d_in[23];

  float* ws = (float*)d_ws;
  const size_t M2 = (size_t)TOK * C;       // 2,097,152 floats (8 MB)
  float* xn   = ws;                        // [0, M2)       K1w, K2r
  float* qb   = ws + M2;                   // [M2, 2M2)     K2w, K3r
  unsigned short* ksb = (unsigned short*)(ws + 2 * M2);  // bf16, first half of [2M2,3M2)
  unsigned short* vsb = (unsigned short*)(ws + 3 * M2);  // bf16, first half of [3M2,4M2)
  float* xio  = ws + 4 * M2;               // [4M2, 5M2)    shortcut (K1w,K4rw), x_buf (K5r,K8r)
  float* aout = ws;                        // alias xn      K3w, K4r
  float* xn2  = ws + M2;                   // alias qb      K5w, K6r
  float* ybuf = ws + 2 * M2;               // alias ks+vs   K6w, K7r, K8r  [2M2,4M2)
  float* ycb  = ws + 5 * M2;               // [5M2, 7M2)    K7w, K8r
  // total workspace use: 7 * M2 * 4 B = 56 MB

  k_ln1  <<<TOK / 64, 256, 0, stream>>>(feat, ln1g, ln1b, xn, xio);
  k_qkv  <<<TOK / 64, 256, 0, stream>>>(xn, wq, bq, wk, bk, wv, bv, qb, ksb, vsb);
  k_attn <<<TOK / 4, 256, 0, stream>>>(qb, ksb, vsb, widx, dprob, kpe, vpe, rpe, aout);
  k_proj <<<TOK / 64, 256, 0, stream>>>(aout, pw, pb, xio);
  k_ln2  <<<TOK / 16, 256, 0, stream>>>(xio, ln2g, ln2b, xn2);
  k_fc1  <<<dim3(TOK / 64, 2), 256, 0, stream>>>(xn2, f1w, f1b, ybuf);
  k_dwconv<<<2048, 256, 0, stream>>>(ybuf, dww, dwb, ycb);
  k_fc2  <<<TOK / 64, 256, 0, stream>>>(ybuf, ycb, f2w, f2b, xio, (float*)d_out);
}

// Round 3
// 222.240 us; speedup vs baseline: 1.5264x; 1.2988x over previous
//
#include <hip/hip_runtime.h>
#include <math.h>

#define TOK   16384   // Bf * hw
#define HW    4096
#define C     128
#define D     64
#define HID   256

constexpr float LN_EPS = 1e-5f;
constexpr float EPS_R  = 1e-10f;
constexpr float QSCALE = 0.08838834764831845f; // 128^-0.5

typedef __attribute__((ext_vector_type(8))) short  bf16x8;
typedef __attribute__((ext_vector_type(4))) float  f32x4;
#define MFMA16(a, b, c) __builtin_amdgcn_mfma_f32_16x16x32_bf16((a), (b), (c), 0, 0, 0)

__device__ __forceinline__ float bflo(unsigned u) { return __uint_as_float(u << 16); }
__device__ __forceinline__ float bfhi(unsigned u) { return __uint_as_float(u & 0xffff0000u); }
__device__ __forceinline__ float bfu(unsigned short u) { return __uint_as_float((unsigned)u << 16); }
__device__ __forceinline__ unsigned short f2bf(float f) {
  unsigned u = __float_as_uint(f);
  unsigned r = (u + 0x7fffu + ((u >> 16) & 1u)) >> 16;
  return (unsigned short)r;
}
__device__ __forceinline__ float gelu_exact(float x) {
  return 0.5f * x * (1.0f + erff(x * 0.7071067811865476f));
}

// ---------------- K0: weight prep -> bf16, transposed Wt[n][k] --------------------
// layout in wt: [wqT 16384][wkT 16384][wvT 16384][pwT 16384][f1wT 32768][f2wT 32768]
__global__ __launch_bounds__(256) void k_prep(const float* __restrict__ wq,
    const float* __restrict__ wk, const float* __restrict__ wv,
    const float* __restrict__ pw, const float* __restrict__ f1w,
    const float* __restrict__ f2w, unsigned short* __restrict__ wt) {
  int id = blockIdx.x * 256 + threadIdx.x;
  if (id < 16384) {
    int n = id >> 7, k = id & 127;
    wt[id] = f2bf(wq[k * 128 + n]);
  } else if (id < 32768) {
    int e = id - 16384; int n = e >> 7, k = e & 127;
    wt[id] = f2bf(wk[k * 128 + n]);
  } else if (id < 49152) {
    int e = id - 32768; int n = e >> 7, k = e & 127;
    wt[id] = f2bf(wv[k * 128 + n]);
  } else if (id < 65536) {
    int e = id - 49152; int n = e >> 7, k = e & 127;
    wt[id] = f2bf(pw[k * 128 + n]);
  } else if (id < 98304) {
    int e = id - 65536; int n = e >> 7, k = e & 127;   // n in [0,256), k in [0,128)
    wt[id] = f2bf(f1w[k * 256 + n]);
  } else if (id < 131072) {
    int e = id - 98304; int n = e >> 8, k = e & 255;   // n in [0,128), k in [0,256)
    wt[id] = f2bf(f2w[k * 128 + n]);
  }
}

// ---------------- K1: transpose (NCHW -> token-major) + LayerNorm1 ----------------
__global__ __launch_bounds__(256) void k_ln1(const float* __restrict__ feat,
    const float* __restrict__ g, const float* __restrict__ b,
    unsigned short* __restrict__ xnb, float* __restrict__ xtm) {
  __shared__ float tile[64][C + 1];
  int t0 = blockIdx.x * 64;
  int n = t0 / HW, i0 = t0 % HW;
  int tid = threadIdx.x;
  const float* fb = feat + (size_t)n * C * HW;
  for (int e = tid; e < 64 * C; e += 256) {
    int ch = e >> 6, ii = e & 63;
    tile[ii][ch] = fb[(size_t)ch * HW + i0 + ii];
  }
  __syncthreads();
  int wave = tid >> 6, lane = tid & 63;
  for (int tkn = wave; tkn < 64; tkn += 4) {
    float a0 = tile[tkn][lane];
    float a1 = tile[tkn][lane + 64];
    float s = a0 + a1;
    for (int off = 32; off; off >>= 1) s += __shfl_xor(s, off, 64);
    float mean = s * (1.0f / 128.0f);
    float d0 = a0 - mean, d1 = a1 - mean;
    float v = d0 * d0 + d1 * d1;
    for (int off = 32; off; off >>= 1) v += __shfl_xor(v, off, 64);
    float rstd = rsqrtf(v * (1.0f / 128.0f) + LN_EPS);
    size_t ro = (size_t)(t0 + tkn) * C;
    xnb[ro + lane]      = f2bf(d0 * rstd * g[lane] + b[lane]);
    xnb[ro + lane + 64] = f2bf(d1 * rstd * g[lane + 64] + b[lane + 64]);
    xtm[ro + lane]      = a0;
    xtm[ro + lane + 64] = a1;
  }
}

// ---------------- K2: QKV GEMM via MFMA (blockIdx.y selects q/k/v) ----------------
__global__ __launch_bounds__(256) void k_qkv(const unsigned short* __restrict__ xnb,
    const unsigned short* __restrict__ wt,
    const float* __restrict__ bq, const float* __restrict__ bk,
    const float* __restrict__ bv, float* __restrict__ q,
    unsigned short* __restrict__ ksw, unsigned short* __restrict__ vsw) {
  int w = threadIdx.x >> 6, lane = threadIdx.x & 63;
  int q4 = lane >> 4, m = lane & 15;
  int t0 = blockIdx.x * 64 + w * 16;
  int wsel = blockIdx.y;
  const unsigned short* Wt = wt + wsel * 16384;
  const unsigned short* ap = xnb + (size_t)(t0 + m) * C + q4 * 8;
  bf16x8 a[4];
  #pragma unroll
  for (int ks = 0; ks < 4; ks++) a[ks] = *(const bf16x8*)(ap + ks * 32);
  f32x4 acc[8];
  #pragma unroll
  for (int nt = 0; nt < 8; nt++) acc[nt] = (f32x4){0.f, 0.f, 0.f, 0.f};
  #pragma unroll
  for (int nt = 0; nt < 8; nt++) {
    const unsigned short* bp = Wt + (size_t)(nt * 16 + m) * C + q4 * 8;
    #pragma unroll
    for (int ks = 0; ks < 4; ks++) {
      bf16x8 bfrag = *(const bf16x8*)(bp + ks * 32);
      acc[nt] = MFMA16(a[ks], bfrag, acc[nt]);
    }
  }
  if (wsel == 0) {
    #pragma unroll
    for (int nt = 0; nt < 8; nt++) {
      int col = nt * 16 + m;
      float bb = bq[col];
      #pragma unroll
      for (int reg = 0; reg < 4; reg++) {
        int row = t0 + q4 * 4 + reg;
        q[(size_t)row * C + col] = (acc[nt][reg] + bb) * QSCALE;
      }
    }
  } else {
    const float* B = (wsel == 1) ? bk : bv;
    unsigned short* O = (wsel == 1) ? ksw : vsw;
    int n = t0 >> 12, i0 = t0 & 4095;
    int tsw = ((n ^ 1) << 12) + i0;
    #pragma unroll
    for (int nt = 0; nt < 8; nt++) {
      int col = nt * 16 + m;
      float bb = B[col];
      #pragma unroll
      for (int reg = 0; reg < 4; reg++) {
        int row = tsw + q4 * 4 + reg;
        O[(size_t)row * C + col] = f2bf(acc[nt][reg] + bb);
      }
    }
  }
}

// ---------------- K3: gather attention, bf16 K/V, coalesced, no LDS ---------------
__global__ __launch_bounds__(256) void k_attn(const float* __restrict__ q,
    const unsigned short* __restrict__ ksw, const unsigned short* __restrict__ vsw,
    const int* __restrict__ widx, const float* __restrict__ dprob,
    const float* __restrict__ kpe, const float* __restrict__ vpe,
    const float* __restrict__ rpe, unsigned short* __restrict__ aoutb) {
  int lane = threadIdx.x & 63;
  int wave = threadIdx.x >> 6;
  int token = blockIdx.x * 4 + wave;
  int n = token >> 12;
  const unsigned short* Kb = ksw + (size_t)n * HW * C;
  const unsigned short* Vb = vsw + (size_t)n * HW * C;
  int g = lane >> 3, s = lane & 7;
  float qreg[16];
  const float* qp = q + (size_t)token * C + s * 16;
  #pragma unroll
  for (int i = 0; i < 4; i++) {
    float4 t = *(const float4*)(qp + i * 4);
    qreg[i * 4 + 0] = t.x; qreg[i * 4 + 1] = t.y;
    qreg[i * 4 + 2] = t.z; qreg[i * 4 + 3] = t.w;
  }
  float qpe = 0.f;
  #pragma unroll
  for (int i = 0; i < 16; i++) qpe += qreg[i];
  qpe += __shfl_xor(qpe, 1, 64);
  qpe += __shfl_xor(qpe, 2, 64);
  qpe += __shfl_xor(qpe, 4, 64);
  int myidx = widx[token * D + lane];
  float mydp = dprob[token * D + lane];
  float mycost = 0.f;
  #pragma unroll
  for (int pass = 0; pass < 8; ++pass) {
    int row = __shfl(myidx, pass * 8 + g, 64);
    const unsigned short* kr = Kb + (size_t)row * C + s * 16;
    uint4 ka = *(const uint4*)(kr);
    uint4 kb = *(const uint4*)(kr + 8);
    float p;
    p  = bflo(ka.x) * qreg[0]  + bfhi(ka.x) * qreg[1];
    p += bflo(ka.y) * qreg[2]  + bfhi(ka.y) * qreg[3];
    p += bflo(ka.z) * qreg[4]  + bfhi(ka.z) * qreg[5];
    p += bflo(ka.w) * qreg[6]  + bfhi(ka.w) * qreg[7];
    p += bflo(kb.x) * qreg[8]  + bfhi(kb.x) * qreg[9];
    p += bflo(kb.y) * qreg[10] + bfhi(kb.y) * qreg[11];
    p += bflo(kb.z) * qreg[12] + bfhi(kb.z) * qreg[13];
    p += bflo(kb.w) * qreg[14] + bfhi(kb.w) * qreg[15];
    p += __shfl_xor(p, 1, 64);
    p += __shfl_xor(p, 2, 64);
    p += __shfl_xor(p, 4, 64);
    float t = __shfl(p, (lane & 7) << 3, 64);
    if (pass == g) mycost = t;
  }
  mycost += qpe * kpe[lane] + rpe[lane];
  float mx = mycost;
  for (int off = 32; off; off >>= 1) mx = fmaxf(mx, __shfl_xor(mx, off, 64));
  float e = __expf(mycost - mx);
  float ssum = e;
  for (int off = 32; off; off >>= 1) ssum += __shfl_xor(ssum, off, 64);
  float attn = (e / ssum) * mydp;
  float s2 = attn;
  for (int off = 32; off; off >>= 1) s2 += __shfl_xor(s2, off, 64);
  attn = (attn + EPS_R) / (s2 + EPS_R);
  float vpt = attn * vpe[lane];
  for (int off = 32; off; off >>= 1) vpt += __shfl_xor(vpt, off, 64);
  float o0 = vpt, o1 = vpt;
  #pragma unroll 8
  for (int kk = 0; kk < D; ++kk) {
    int row = __shfl(myidx, kk, 64);
    float a = __shfl(attn, kk, 64);
    unsigned v = *(const unsigned*)(Vb + (size_t)row * C + lane * 2);
    o0 += a * bflo(v);
    o1 += a * bfhi(v);
  }
  unsigned pk = (unsigned)f2bf(o0) | ((unsigned)f2bf(o1) << 16);
  *(unsigned*)(aoutb + (size_t)token * C + lane * 2) = pk;
}

// ---------------- K4: proj GEMM (MFMA) + residual + fused LayerNorm2 --------------
__global__ __launch_bounds__(256) void k_projln(const unsigned short* __restrict__ aoutb,
    const unsigned short* __restrict__ wt, const float* __restrict__ pb,
    float* __restrict__ xio, const float* __restrict__ g2,
    const float* __restrict__ b2, unsigned short* __restrict__ xn2b) {
  int w = threadIdx.x >> 6, lane = threadIdx.x & 63;
  int q4 = lane >> 4, m = lane & 15;
  int t0 = blockIdx.x * 64 + w * 16;
  const unsigned short* Wt = wt + 3 * 16384;  // pwT
  const unsigned short* ap = aoutb + (size_t)(t0 + m) * C + q4 * 8;
  bf16x8 a[4];
  #pragma unroll
  for (int ks = 0; ks < 4; ks++) a[ks] = *(const bf16x8*)(ap + ks * 32);
  f32x4 acc[8];
  #pragma unroll
  for (int nt = 0; nt < 8; nt++) acc[nt] = (f32x4){0.f, 0.f, 0.f, 0.f};
  #pragma unroll
  for (int nt = 0; nt < 8; nt++) {
    const unsigned short* bp = Wt + (size_t)(nt * 16 + m) * C + q4 * 8;
    #pragma unroll
    for (int ks = 0; ks < 4; ks++) {
      bf16x8 bfrag = *(const bf16x8*)(bp + ks * 32);
      acc[nt] = MFMA16(a[ks], bfrag, acc[nt]);
    }
  }
  // r = acc + bias + shortcut; accumulate row stats
  float s1[4] = {0.f, 0.f, 0.f, 0.f}, s2[4] = {0.f, 0.f, 0.f, 0.f};
  #pragma unroll
  for (int nt = 0; nt < 8; nt++) {
    int col = nt * 16 + m;
    float bb = pb[col];
    #pragma unroll
    for (int reg = 0; reg < 4; reg++) {
      int row = t0 + q4 * 4 + reg;
      float v = acc[nt][reg] + bb + xio[(size_t)row * C + col];
      acc[nt][reg] = v;
      s1[reg] += v;
      s2[reg] += v * v;
    }
  }
  #pragma unroll
  for (int reg = 0; reg < 4; reg++) {
    #pragma unroll
    for (int off = 1; off < 16; off <<= 1) {
      s1[reg] += __shfl_xor(s1[reg], off, 64);
      s2[reg] += __shfl_xor(s2[reg], off, 64);
    }
  }
  float mean[4], rstd[4];
  #pragma unroll
  for (int reg = 0; reg < 4; reg++) {
    mean[reg] = s1[reg] * (1.0f / 128.0f);
    float var = s2[reg] * (1.0f / 128.0f) - mean[reg] * mean[reg];
    rstd[reg] = rsqrtf(var + LN_EPS);
  }
  #pragma unroll
  for (int nt = 0; nt < 8; nt++) {
    int col = nt * 16 + m;
    float gc = g2[col], bc = b2[col];
    #pragma unroll
    for (int reg = 0; reg < 4; reg++) {
      int row = t0 + q4 * 4 + reg;
      float v = acc[nt][reg];
      xio[(size_t)row * C + col] = v;
      xn2b[(size_t)row * C + col] = f2bf((v - mean[reg]) * rstd[reg] * gc + bc);
    }
  }
}

// ---------------- K5: fc1 GEMM (MFMA) + GELU -> bf16 ------------------------------
__global__ __launch_bounds__(256) void k_fc1(const unsigned short* __restrict__ xn2b,
    const unsigned short* __restrict__ wt, const float* __restrict__ f1b,
    unsigned short* __restrict__ y) {
  int w = threadIdx.x >> 6, lane = threadIdx.x & 63;
  int q4 = lane >> 4, m = lane & 15;
  int t0 = blockIdx.x * 64 + w * 16;
  int n0 = blockIdx.y * 128;
  const unsigned short* Wt = wt + 65536 + (size_t)n0 * C;  // f1wT rows [n0, n0+128)
  const unsigned short* ap = xn2b + (size_t)(t0 + m) * C + q4 * 8;
  bf16x8 a[4];
  #pragma unroll
  for (int ks = 0; ks < 4; ks++) a[ks] = *(const bf16x8*)(ap + ks * 32);
  f32x4 acc[8];
  #pragma unroll
  for (int nt = 0; nt < 8; nt++) acc[nt] = (f32x4){0.f, 0.f, 0.f, 0.f};
  #pragma unroll
  for (int nt = 0; nt < 8; nt++) {
    const unsigned short* bp = Wt + (size_t)(nt * 16 + m) * C + q4 * 8;
    #pragma unroll
    for (int ks = 0; ks < 4; ks++) {
      bf16x8 bfrag = *(const bf16x8*)(bp + ks * 32);
      acc[nt] = MFMA16(a[ks], bfrag, acc[nt]);
    }
  }
  #pragma unroll
  for (int nt = 0; nt < 8; nt++) {
    int col = n0 + nt * 16 + m;
    float bb = f1b[col];
    #pragma unroll
    for (int reg = 0; reg < 4; reg++) {
      int row = t0 + q4 * 4 + reg;
      y[(size_t)row * HID + col] = f2bf(gelu_exact(acc[nt][reg] + bb));
    }
  }
}

// ---------------- K6: depthwise 5x5 conv + GELU (bf16 in/out, token-major) --------
__global__ __launch_bounds__(256) void k_dwconv(const unsigned short* __restrict__ y,
    const float* __restrict__ w, const float* __restrict__ bias,
    unsigned short* __restrict__ yc) {
  __shared__ float tile[20 * 20][8];
  __shared__ float wl[8][25];
  __shared__ float bl[8];
  int bid = blockIdx.x;
  int tile_id = bid & 15;
  int cb = (bid >> 4) & 31;
  int n = bid >> 9;
  int ty = (tile_id >> 2) * 16, tx = (tile_id & 3) * 16;
  int ch0 = cb * 8;
  int tid = threadIdx.x;
  if (tid < 200) wl[tid / 25][tid % 25] = w[(size_t)(ch0 + tid / 25) * 25 + tid % 25];
  if (tid < 8) bl[tid] = bias[ch0 + tid];
  const unsigned short* yb = y + (size_t)n * HW * HID;
  for (int e = tid; e < 400 * 8; e += 256) {
    int cc = e & 7;
    int p = e >> 3;
    int py = p / 20, px = p % 20;
    int gy = ty + py - 2, gx = tx + px - 2;
    float v = 0.f;
    if (gy >= 0 && gy < 64 && gx >= 0 && gx < 64)
      v = bfu(yb[(size_t)(gy * 64 + gx) * HID + ch0 + cc]);
    tile[p][cc] = v;
  }
  __syncthreads();
  int cc = tid & 7;
  int xx = (tid >> 3) & 15;
  int yg = tid >> 7;
  float wreg[25];
  #pragma unroll
  for (int k = 0; k < 25; k++) wreg[k] = wl[cc][k];
  float bb = bl[cc];
  for (int j = 0; j < 8; ++j) {
    int yy = yg * 8 + j;
    float acc = 0.f;
    #pragma unroll
    for (int dy = 0; dy < 5; ++dy)
      #pragma unroll
      for (int dx = 0; dx < 5; ++dx)
        acc += wreg[dy * 5 + dx] * tile[(yy + dy) * 20 + (xx + dx)][cc];
    acc = gelu_exact(acc + bb);
    yc[(size_t)(n * HW + (ty + yy) * 64 + tx + xx) * HID + ch0 + cc] = f2bf(acc);
  }
}

// ---------------- K7: fc2 GEMM (MFMA) on (y + yc) + final residual -> out ---------
__global__ __launch_bounds__(256) void k_fc2(const unsigned short* __restrict__ y,
    const unsigned short* __restrict__ ycg, const unsigned short* __restrict__ wt,
    const float* __restrict__ f2b, const float* __restrict__ xio,
    float* __restrict__ outp) {
  int w = threadIdx.x >> 6, lane = threadIdx.x & 63;
  int q4 = lane >> 4, m = lane & 15;
  int t0 = blockIdx.x * 64 + w * 16;
  const unsigned short* Wt = wt + 98304;  // f2wT [128][256]
  const unsigned short* ap = y + (size_t)(t0 + m) * HID + q4 * 8;
  const unsigned short* cp = ycg + (size_t)(t0 + m) * HID + q4 * 8;
  union U { bf16x8 v; unsigned short s[8]; };
  bf16x8 a[8];
  #pragma unroll
  for (int ks = 0; ks < 8; ks++) {
    U ua, uc, ur;
    ua.v = *(const bf16x8*)(ap + ks * 32);
    uc.v = *(const bf16x8*)(cp + ks * 32);
    #pragma unroll
    for (int j = 0; j < 8; j++) ur.s[j] = f2bf(bfu(ua.s[j]) + bfu(uc.s[j]));
    a[ks] = ur.v;
  }
  f32x4 acc[8];
  #pragma unroll
  for (int nt = 0; nt < 8; nt++) acc[nt] = (f32x4){0.f, 0.f, 0.f, 0.f};
  #pragma unroll
  for (int nt = 0; nt < 8; nt++) {
    const unsigned short* bp = Wt + (size_t)(nt * 16 + m) * HID + q4 * 8;
    #pragma unroll
    for (int ks = 0; ks < 8; ks++) {
      bf16x8 bfrag = *(const bf16x8*)(bp + ks * 32);
      acc[nt] = MFMA16(a[ks], bfrag, acc[nt]);
    }
  }
  #pragma unroll
  for (int nt = 0; nt < 8; nt++) {
    int col = nt * 16 + m;
    float bb = f2b[col];
    #pragma unroll
    for (int reg = 0; reg < 4; reg++) {
      int row = t0 + q4 * 4 + reg;
      outp[(size_t)row * C + col] = acc[nt][reg] + bb + xio[(size_t)row * C + col];
    }
  }
}

extern "C" void kernel_launch(void* const* d_in, const int* in_sizes, int n_in,
                              void* d_out, int out_size, void* d_ws, size_t ws_size,
                              hipStream_t stream) {
  (void)in_sizes; (void)n_in; (void)out_size; (void)ws_size;
  const float* feat  = (const float*)d_in[0];
  const int*   widx  = (const int*)d_in[1];
  const float* dprob = (const float*)d_in[2];
  const float* ln1g  = (const float*)d_in[3];
  const float* ln1b  = (const float*)d_in[4];
  const float* wq    = (const float*)d_in[5];
  const float* bq    = (const float*)d_in[6];
  const float* wk    = (const float*)d_in[7];
  const float* bk    = (const float*)d_in[8];
  const float* wv    = (const float*)d_in[9];
  const float* bv    = (const float*)d_in[10];
  const float* kpe   = (const float*)d_in[11];
  const float* vpe   = (const float*)d_in[12];
  const float* rpe   = (const float*)d_in[13];
  const float* pw    = (const float*)d_in[14];
  const float* pb    = (const float*)d_in[15];
  const float* ln2g  = (const float*)d_in[16];
  const float* ln2b  = (const float*)d_in[17];
  const float* f1w   = (const float*)d_in[18];
  const float* f1b   = (const float*)d_in[19];
  const float* dww   = (const float*)d_in[20];
  const float* dwb   = (const float*)d_in[21];
  const float* f2w   = (const float*)d_in[22];
  const float* f2b   = (const float*)d_in[23];

  float* ws = (float*)d_ws;
  const size_t M2 = (size_t)TOK * C;  // 2,097,152 floats (8 MB)
  // fp32 buffers
  float* qb  = ws;                        // [0,   M2)  q (fp32, scaled)
  float* xio = ws + M2;                   // [M2, 2M2)  shortcut / residual stream
  // bf16 buffers (each M2 ushorts = M2/2 floats)
  unsigned short* xnb   = (unsigned short*)(ws + 2 * M2);            // ln1 out
  unsigned short* ksb   = (unsigned short*)(ws + 2 * M2 + M2 / 2);   // K (swapped)
  unsigned short* vsb   = (unsigned short*)(ws + 3 * M2);            // V (swapped)
  unsigned short* aoutb = (unsigned short*)(ws + 3 * M2 + M2 / 2);   // attn out
  unsigned short* xn2b  = (unsigned short*)(ws + 4 * M2);            // ln2 out
  unsigned short* yb    = (unsigned short*)(ws + 4 * M2 + M2 / 2);   // fc1 out (TOK x 256) = 2*M2 ushorts
  unsigned short* ycgb  = (unsigned short*)(ws + 5 * M2 + M2 / 2);   // dwconv out       = 2*M2 ushorts
  unsigned short* wtb   = (unsigned short*)(ws + 6 * M2 + M2 / 2);   // weights bf16 (131072 ushorts)
  // total: 6.5*M2*4 + 256KB ≈ 52.3 MB

  k_prep  <<<512, 256, 0, stream>>>(wq, wk, wv, pw, f1w, f2w, wtb);
  k_ln1   <<<TOK / 64, 256, 0, stream>>>(feat, ln1g, ln1b, xnb, xio);
  k_qkv   <<<dim3(TOK / 64, 3), 256, 0, stream>>>(xnb, wtb, bq, bk, bv, qb, ksb, vsb);
  k_attn  <<<TOK / 4, 256, 0, stream>>>(qb, ksb, vsb, widx, dprob, kpe, vpe, rpe, aoutb);
  k_projln<<<TOK / 64, 256, 0, stream>>>(aoutb, wtb, pb, xio, ln2g, ln2b, xn2b);
  k_fc1   <<<dim3(TOK / 64, 2), 256, 0, stream>>>(xn2b, wtb, f1b, yb);
  k_dwconv<<<2048, 256, 0, stream>>>(yb, dww, dwb, ycgb);
  k_fc2   <<<TOK / 64, 256, 0, stream>>>(yb, ycgb, wtb, f2b, xio, (float*)d_out);
}